// Round 9
// baseline (843.501 us; speedup 1.0000x reference)
//
#include <hip/hip_runtime.h>
#include <hip/hip_bf16.h>
#include <cstdint>
#include <cstddef>

// Problem constants (fixed by the reference)
#define NB 8
#define NT 256
#define NU 64
#define DJ 512      // JOINT_D
#define DV 1024     // VOCAB
#define DK 256      // ENC_D == PRED_D

#define TPB 4       // bt tiles per block (joint kernel)

typedef __attribute__((ext_vector_type(8))) short short8;
typedef __attribute__((ext_vector_type(4))) float floatx4;

__device__ __forceinline__ unsigned short f2bf(float x) {
    unsigned int u = __float_as_uint(x);
    u += 0x7fffu + ((u >> 16) & 1u);   // round-to-nearest-even
    return (unsigned short)(u >> 16);
}

__device__ __forceinline__ ushort4 tanh4_bf(float4 e, float4 d) {
    float x0 = e.x + d.x, x1 = e.y + d.y, x2 = e.z + d.z, x3 = e.w + d.w;
    ushort4 o;
    o.x = f2bf(1.f - 2.f / (__expf(2.f * x0) + 1.f));
    o.y = f2bf(1.f - 2.f / (__expf(2.f * x1) + 1.f));
    o.z = f2bf(1.f - 2.f / (__expf(2.f * x2) + 1.f));
    o.w = f2bf(1.f - 2.f / (__expf(2.f * x3) + 1.f));
    return o;
}

// ---------------------------------------------------------------------------
// Kernel 1: enc_proj = enc @ W1[:, :256]^T + b1   (2048 x 512)
//           dec_proj = dec @ W1[:, 256:]^T        (512  x 512)
// (unchanged — ~15-25 us, not the bottleneck)
// ---------------------------------------------------------------------------
__global__ __launch_bounds__(256) void stage1_gemm(
    const float* __restrict__ enc, const float* __restrict__ dec,
    const float* __restrict__ W1, const float* __restrict__ b1,
    float* __restrict__ enc_proj, float* __restrict__ dec_proj)
{
    __shared__ float As[64][17];
    __shared__ float Bs[16][65];

    const int n0 = blockIdx.x * 64;
    const int m0 = blockIdx.y * 64;
    const bool is_enc = (m0 < NB * NT);
    const float* A = is_enc ? enc : dec;
    const int arow0 = is_enc ? m0 : (m0 - NB * NT);
    const int koff  = is_enc ? 0 : DK;
    float* C = is_enc ? enc_proj : dec_proj;

    const int tid = threadIdx.x;
    const int kk = tid & 15;
    const int grp = tid >> 4;
    const int tx = tid & 15;
    const int ty = tid >> 4;

    float acc[4][4] = {};

    for (int k0 = 0; k0 < DK; k0 += 16) {
        #pragma unroll
        for (int g = 0; g < 4; g++) {
            As[grp + g * 16][kk] = A[(size_t)(arow0 + grp + g * 16) * DK + k0 + kk];
            Bs[kk][grp + g * 16] = W1[(size_t)(n0 + grp + g * 16) * DJ + koff + k0 + kk];
        }
        __syncthreads();
        #pragma unroll
        for (int k = 0; k < 16; k++) {
            float av[4], bv[4];
            #pragma unroll
            for (int i = 0; i < 4; i++) av[i] = As[ty * 4 + i][k];
            #pragma unroll
            for (int j = 0; j < 4; j++) bv[j] = Bs[k][tx * 4 + j];
            #pragma unroll
            for (int i = 0; i < 4; i++)
                #pragma unroll
                for (int j = 0; j < 4; j++)
                    acc[i][j] = fmaf(av[i], bv[j], acc[i][j]);
        }
        __syncthreads();
    }

    float4 bias = make_float4(0.f, 0.f, 0.f, 0.f);
    if (is_enc) bias = *(const float4*)&b1[n0 + tx * 4];
    #pragma unroll
    for (int i = 0; i < 4; i++) {
        const int row = arow0 + ty * 4 + i;
        float4 v;
        v.x = acc[i][0] + bias.x;
        v.y = acc[i][1] + bias.y;
        v.z = acc[i][2] + bias.z;
        v.w = acc[i][3] + bias.w;
        *(float4*)&C[(size_t)row * DJ + n0 + tx * 4] = v;
    }
}

// ---------------------------------------------------------------------------
// Kernel 2: W2 fp32 -> bf16 (1024 x 512)
// ---------------------------------------------------------------------------
__global__ __launch_bounds__(256) void convert_w2(
    const float* __restrict__ W2, unsigned short* __restrict__ W2b)
{
    const int i = (blockIdx.x * 256 + threadIdx.x) * 4;
    float4 v = *(const float4*)(W2 + i);
    ushort4 o;
    o.x = f2bf(v.x); o.y = f2bf(v.y); o.z = f2bf(v.z); o.w = f2bf(v.w);
    *(ushort4*)(W2b + i) = o;
}

// ---------------------------------------------------------------------------
// Kernel 3: fused joint + log_softmax, TILE-LEVEL SOFTWARE PIPELINE.
//
// Round-6 post-mortem: B-prefetch helped (450->401us) but the kernel is
// phase-serialized: per-CU floors are MFMA 66us (4.85cy/mfma per CU,
// matches MfmaUtil 14.3% = 13.7% of peak), HBM writes ~85-100us, W2b L2
// reads ~58us — overlapped ceiling ~100us, measured 401 because with one
// block/CU the barrier-separated phases use one resource at a time.
//
// This version: each block processes TPB=4 consecutive bt tiles with
// double-buffered ha (2 x 64KB LDS, gfx950 allows >64KB/WG):
//  - phase-1 of tile t+1 (dec load + tanh + swizzled LDS write, one row
//    per K-step) is embedded in the K-loop of tile t -> VALU/trans and
//    L2 loads hide under the MFMA pipe;
//  - tile t's nontemporal store burst drains under tile t+1's K-loop;
//  - 2 barriers per tile (epilogue reduction); they also publish the
//    next ha buffer.
// Registers: 128 acc + 64 bv + 16 av + 12 P1 + ~30 misc ~= 250 <= 256
// (2 waves/SIMD). Watch for scratch>0 next round.
// ---------------------------------------------------------------------------
__global__ __launch_bounds__(512, 2) void joint_kernel(
    const float* __restrict__ enc_proj, const float* __restrict__ dec_proj,
    const unsigned short* __restrict__ W2b, const float* __restrict__ b2,
    float* __restrict__ out)
{
    // ha: 2 buffers of [64][512] bf16 (65536 B each) | wred [64][8] | rowoff [64]
    __shared__ __align__(16) unsigned char smem[133376];
    unsigned short* ha = (unsigned short*)smem;
    float* wred     = (float*)(smem + 131072);
    float* rowoff_s = (float*)(smem + 133120);

    const int bt0 = blockIdx.x * TPB;
    const int tid = threadIdx.x;

    // phase-1 mapping: thread -> (col chunk j0, row group ug)
    const int j0 = (tid & 127) * 4;
    const int ug = tid >> 7;
    const int chunk = j0 >> 3;
    const int wi = j0 & 7;

    // MFMA mapping
    const int w = tid >> 6;
    const int lane = tid & 63;
    const int q = lane >> 4;
    const int nn = lane & 15;
    const int wbase = w * 128;
    const unsigned short* pB0 = W2b + (size_t)(wbase + nn * 4) * DJ + q * 8;
    const unsigned short* pB1 = pB0 + (size_t)64 * DJ;

    // ---- Prologue: phase-1 for tile 0 into ha buffer 0 ----
    {
        const int bt = bt0;
        const int b = bt >> 8;
        const float4 e = *(const float4*)(enc_proj + (size_t)bt * DJ + j0);
        const float* dpp = dec_proj + (size_t)(b * NU + ug * 16) * DJ + j0;
        #pragma unroll 4
        for (int i2 = 0; i2 < 16; i2++) {
            const int u = ug * 16 + i2;
            float4 d = *(const float4*)(dpp + (size_t)i2 * DJ);
            *(ushort4*)(ha + (size_t)u * DJ + (((chunk ^ (u & 7)) << 3) + wi)) =
                tanh4_bf(e, d);
        }
    }
    __syncthreads();

    for (int t = 0; t < TPB; t++) {
        const int bt = bt0 + t;
        const int cur = t & 1;
        unsigned short* hac = ha + cur * 32768;          // current A tile
        unsigned short* han = ha + (cur ^ 1) * 32768;    // next A tile (being built)
        const bool hasNext = (t + 1 < TPB);

        // next-tile phase-1 state
        float4 e_n = make_float4(0.f, 0.f, 0.f, 0.f);
        const float* dpn = nullptr;
        float4 dcur = make_float4(0.f, 0.f, 0.f, 0.f);
        float4 dnxt;
        if (hasNext) {
            const int btn = bt + 1;
            const int bn = btn >> 8;
            e_n = *(const float4*)(enc_proj + (size_t)btn * DJ + j0);
            dpn = dec_proj + (size_t)(bn * NU + ug * 16) * DJ + j0;
            dcur = *(const float4*)(dpn);                // row 0
        }

        floatx4 acc[4][8];
        #pragma unroll
        for (int rt = 0; rt < 4; rt++)
            #pragma unroll
            for (int ct = 0; ct < 8; ct++)
                acc[rt][ct] = (floatx4){0.f, 0.f, 0.f, 0.f};

        short8 bv0[8], bv1[8];
        short8 av[4];

        #pragma unroll
        for (int c4 = 0; c4 < 4; c4++) {
            bv0[c4]     = *(const short8*)(pB0 + (size_t)c4 * DJ);
            bv0[4 + c4] = *(const short8*)(pB1 + (size_t)c4 * DJ);
        }

        // ---- K-loop: 16 steps of k=32, B double-buffered, P1(t+1) embedded ----
        for (int ks = 0; ks < 16; ks += 2) {
            // prefetch B for step ks+1
            #pragma unroll
            for (int c4 = 0; c4 < 4; c4++) {
                bv1[c4]     = *(const short8*)(pB0 + (size_t)c4 * DJ + (ks + 1) * 32);
                bv1[4 + c4] = *(const short8*)(pB1 + (size_t)c4 * DJ + (ks + 1) * 32);
            }
            // embedded P1: load row ks+1, tanh+write row ks
            if (hasNext) {
                dnxt = *(const float4*)(dpn + (size_t)(ks + 1) * DJ);
                const int u = ug * 16 + ks;
                *(ushort4*)(han + (size_t)u * DJ + (((chunk ^ (u & 7)) << 3) + wi)) =
                    tanh4_bf(e_n, dcur);
            }
            // compute step ks with bv0
            #pragma unroll
            for (int rt = 0; rt < 4; rt++) {
                const int u2 = rt * 16 + nn;
                const int c = ((ks * 4 + q) ^ (u2 & 7)) << 3;
                av[rt] = *(const short8*)(hac + (size_t)u2 * DJ + c);
            }
            #pragma unroll
            for (int ct = 0; ct < 8; ct++)
                #pragma unroll
                for (int rt = 0; rt < 4; rt++)
                    acc[rt][ct] = __builtin_amdgcn_mfma_f32_16x16x32_bf16(
                        av[rt], bv0[ct], acc[rt][ct], 0, 0, 0);

            // prefetch B for step ks+2
            if (ks + 2 < 16) {
                #pragma unroll
                for (int c4 = 0; c4 < 4; c4++) {
                    bv0[c4]     = *(const short8*)(pB0 + (size_t)c4 * DJ + (ks + 2) * 32);
                    bv0[4 + c4] = *(const short8*)(pB1 + (size_t)c4 * DJ + (ks + 2) * 32);
                }
            }
            // embedded P1: load row ks+2, tanh+write row ks+1
            if (hasNext) {
                if (ks + 2 < 16) dcur = *(const float4*)(dpn + (size_t)(ks + 2) * DJ);
                const int u = ug * 16 + ks + 1;
                *(ushort4*)(han + (size_t)u * DJ + (((chunk ^ (u & 7)) << 3) + wi)) =
                    tanh4_bf(e_n, dnxt);
            }
            // compute step ks+1 with bv1
            #pragma unroll
            for (int rt = 0; rt < 4; rt++) {
                const int u2 = rt * 16 + nn;
                const int c = (((ks + 1) * 4 + q) ^ (u2 & 7)) << 3;
                av[rt] = *(const short8*)(hac + (size_t)u2 * DJ + c);
            }
            #pragma unroll
            for (int ct = 0; ct < 8; ct++)
                #pragma unroll
                for (int rt = 0; rt < 4; rt++)
                    acc[rt][ct] = __builtin_amdgcn_mfma_f32_16x16x32_bf16(
                        av[rt], bv1[ct], acc[rt][ct], 0, 0, 0);
        }

        // ---- Epilogue: bias, row-sum of exp, log-softmax offset ----
        float b2a[8];
        *(float4*)&b2a[0] = *(const float4*)(b2 + wbase + nn * 4);
        *(float4*)&b2a[4] = *(const float4*)(b2 + wbase + 64 + nn * 4);
        #pragma unroll
        for (int rt = 0; rt < 4; rt++)
            #pragma unroll
            for (int ct = 0; ct < 8; ct++)
                #pragma unroll
                for (int r = 0; r < 4; r++)
                    acc[rt][ct][r] += b2a[ct];

        // per-row sum of exp (no max: |logit| < ~23, fp32-safe)
        #pragma unroll
        for (int rt = 0; rt < 4; rt++) {
            #pragma unroll
            for (int r = 0; r < 4; r++) {
                float s = 0.f;
                #pragma unroll
                for (int ct = 0; ct < 8; ct++) s += __expf(acc[rt][ct][r]);
                #pragma unroll
                for (int mk = 1; mk <= 8; mk <<= 1) s += __shfl_xor(s, mk, 64);
                if (nn == 0) wred[(rt * 16 + q * 4 + r) * 8 + w] = s;
            }
        }
        __syncthreads();                       // b1: wred complete (+ han published)
        if (tid < 64) {
            float4 s0 = *(const float4*)&wred[tid * 8];
            float4 s1 = *(const float4*)&wred[tid * 8 + 4];
            float s = ((s0.x + s0.y) + (s0.z + s0.w)) + ((s1.x + s1.y) + (s1.z + s1.w));
            rowoff_s[tid] = __logf(s);
        }
        __syncthreads();                       // b2: rowoff ready

        // stores: fire-and-forget; drain under next tile's K-loop
        float* outb = out + (size_t)bt * NU * DV;
        #pragma unroll
        for (int rt = 0; rt < 4; rt++) {
            #pragma unroll
            for (int r = 0; r < 4; r++) {
                const int u = rt * 16 + q * 4 + r;
                const float off = rowoff_s[u];
                floatx4 v0, v1;
                v0[0] = acc[rt][0][r] - off; v0[1] = acc[rt][1][r] - off;
                v0[2] = acc[rt][2][r] - off; v0[3] = acc[rt][3][r] - off;
                v1[0] = acc[rt][4][r] - off; v1[1] = acc[rt][5][r] - off;
                v1[2] = acc[rt][6][r] - off; v1[3] = acc[rt][7][r] - off;
                __builtin_nontemporal_store(v0, (floatx4*)(outb + (size_t)u * DV + wbase + nn * 4));
                __builtin_nontemporal_store(v1, (floatx4*)(outb + (size_t)u * DV + wbase + 64 + nn * 4));
            }
        }
    }
}

// ---------------------------------------------------------------------------
extern "C" void kernel_launch(void* const* d_in, const int* in_sizes, int n_in,
                              void* d_out, int out_size, void* d_ws, size_t ws_size,
                              hipStream_t stream) {
    const float* enc = (const float*)d_in[0];   // (8,256,256)
    const float* dec = (const float*)d_in[1];   // (8,64,256)
    const float* W1  = (const float*)d_in[2];   // (512,512)
    const float* b1  = (const float*)d_in[3];   // (512,)
    const float* W2  = (const float*)d_in[4];   // (1024,512)
    const float* b2  = (const float*)d_in[5];   // (1024,)
    float* out = (float*)d_out;                 // (8,256,64,1024)

    // workspace: enc_proj (2048x512 f32) | dec_proj (512x512 f32) | W2 bf16
    float* enc_proj = (float*)d_ws;
    float* dec_proj = enc_proj + (size_t)(NB * NT) * DJ;
    unsigned short* W2b = (unsigned short*)(dec_proj + (size_t)DJ * DJ);

    dim3 g1(8, 40);
    stage1_gemm<<<g1, 256, 0, stream>>>(enc, dec, W1, b1, enc_proj, dec_proj);
    convert_w2<<<512, 256, 0, stream>>>(W2, W2b);
    joint_kernel<<<(NB * NT) / TPB, 512, 0, stream>>>(enc_proj, dec_proj, W2b, b2, out);
}

// Round 11
// 828.407 us; speedup vs baseline: 1.0182x; 1.0182x over previous
//
#include <hip/hip_runtime.h>
#include <hip/hip_bf16.h>
#include <cstdint>
#include <cstddef>

// Problem constants (fixed by the reference)
#define NB 8
#define NT 256
#define NU 64
#define DJ 512      // JOINT_D
#define DV 1024     // VOCAB
#define DK 256      // ENC_D == PRED_D

typedef __attribute__((ext_vector_type(8))) short short8;
typedef __attribute__((ext_vector_type(4))) float floatx4;

__device__ __forceinline__ unsigned short f2bf(float x) {
    unsigned int u = __float_as_uint(x);
    u += 0x7fffu + ((u >> 16) & 1u);   // round-to-nearest-even
    return (unsigned short)(u >> 16);
}

// async global->LDS, 16 bytes per lane (dest = wave-uniform base + lane*16)
__device__ __forceinline__ void gll16(const void* g, void* l) {
    __builtin_amdgcn_global_load_lds(
        (const __attribute__((address_space(1))) unsigned int*)g,
        (__attribute__((address_space(3))) unsigned int*)l, 16, 0, 0);
}

// ---------------------------------------------------------------------------
// Kernel 1: enc_proj = enc @ W1[:, :256]^T + b1   (2048 x 512)
//           dec_proj = dec @ W1[:, 256:]^T        (512  x 512)
// (unchanged — not the bottleneck)
// ---------------------------------------------------------------------------
__global__ __launch_bounds__(256) void stage1_gemm(
    const float* __restrict__ enc, const float* __restrict__ dec,
    const float* __restrict__ W1, const float* __restrict__ b1,
    float* __restrict__ enc_proj, float* __restrict__ dec_proj)
{
    __shared__ float As[64][17];
    __shared__ float Bs[16][65];

    const int n0 = blockIdx.x * 64;
    const int m0 = blockIdx.y * 64;
    const bool is_enc = (m0 < NB * NT);
    const float* A = is_enc ? enc : dec;
    const int arow0 = is_enc ? m0 : (m0 - NB * NT);
    const int koff  = is_enc ? 0 : DK;
    float* C = is_enc ? enc_proj : dec_proj;

    const int tid = threadIdx.x;
    const int kk = tid & 15;
    const int grp = tid >> 4;
    const int tx = tid & 15;
    const int ty = tid >> 4;

    float acc[4][4] = {};

    for (int k0 = 0; k0 < DK; k0 += 16) {
        #pragma unroll
        for (int g = 0; g < 4; g++) {
            As[grp + g * 16][kk] = A[(size_t)(arow0 + grp + g * 16) * DK + k0 + kk];
            Bs[kk][grp + g * 16] = W1[(size_t)(n0 + grp + g * 16) * DJ + koff + k0 + kk];
        }
        __syncthreads();
        #pragma unroll
        for (int k = 0; k < 16; k++) {
            float av[4], bv[4];
            #pragma unroll
            for (int i = 0; i < 4; i++) av[i] = As[ty * 4 + i][k];
            #pragma unroll
            for (int j = 0; j < 4; j++) bv[j] = Bs[k][tx * 4 + j];
            #pragma unroll
            for (int i = 0; i < 4; i++)
                #pragma unroll
                for (int j = 0; j < 4; j++)
                    acc[i][j] = fmaf(av[i], bv[j], acc[i][j]);
        }
        __syncthreads();
    }

    float4 bias = make_float4(0.f, 0.f, 0.f, 0.f);
    if (is_enc) bias = *(const float4*)&b1[n0 + tx * 4];
    #pragma unroll
    for (int i = 0; i < 4; i++) {
        const int row = arow0 + ty * 4 + i;
        float4 v;
        v.x = acc[i][0] + bias.x;
        v.y = acc[i][1] + bias.y;
        v.z = acc[i][2] + bias.z;
        v.w = acc[i][3] + bias.w;
        *(float4*)&C[(size_t)row * DJ + n0 + tx * 4] = v;
    }
}

// ---------------------------------------------------------------------------
// Kernel 2: W2 fp32 -> bf16 (1024 x 512)
// ---------------------------------------------------------------------------
__global__ __launch_bounds__(256) void convert_w2(
    const float* __restrict__ W2, unsigned short* __restrict__ W2b)
{
    const int i = (blockIdx.x * 256 + threadIdx.x) * 4;
    float4 v = *(const float4*)(W2 + i);
    ushort4 o;
    o.x = f2bf(v.x); o.y = f2bf(v.y); o.z = f2bf(v.z); o.w = f2bf(v.w);
    *(ushort4*)(W2b + i) = o;
}

// ---------------------------------------------------------------------------
// Kernel 3: fused joint + log_softmax, B via global_load_lds + counted vmcnt.
//
// Round-9 post-mortem: TPB=4 phase-embedding was NEUTRAL (401->407us,
// MfmaUtil 14% unchanged) and wrecked L2 (FETCH 10->195MB). The K-loop
// itself is the wall: register B-loads with depth-1 prefetch leave the
// wave stalled on vmcnt ~85% of the time regardless of surrounding phases.
//
// Fix (T3/T4 pattern): B is wave-PRIVATE (each wave owns a 128-col W2b
// slice) -> stage it via async global_load_lds into per-wave LDS chunks,
// double-buffered per half-step, with asm counted vmcnt(4) — never
// drain-to-0, NO barriers in the K-loop. Per half-step per wave:
//   {4 gll (next half) | vmcnt(4) | sched_barrier | 4 ds_read_b128 | 16 MFMA}
// LDS: ha 64KB + 2x32KB B = 128KB. Grid back to 2048 (TPB=1) to restore
// the FETCH~10MB L2-resident regime (clean A/B vs round-6's 401us).
// Data path identity: per-lane gll source addr == round-6 bv load addr;
// LDS round-trip is lane*16 in / lane*16 out.
// ---------------------------------------------------------------------------
__global__ __launch_bounds__(512, 2) void joint_kernel(
    const float* __restrict__ enc_proj, const float* __restrict__ dec_proj,
    const unsigned short* __restrict__ W2b, const float* __restrict__ b2,
    float* __restrict__ out)
{
    // [0,64K): ha 64x512 bf16 swizzled; [64K,96K): Bbuf0; [96K,128K): Bbuf1
    // after K-loop: wred/rowoff overlay ha region
    __shared__ __align__(16) unsigned char smem[131072];
    unsigned short* ha = (unsigned short*)smem;
    unsigned short* Bb0 = (unsigned short*)(smem + 65536);
    unsigned short* Bb1 = (unsigned short*)(smem + 98304);

    const int bt = blockIdx.x;            // b*256 + t
    const int b = bt >> 8;
    const int tid = threadIdx.x;

    // ---- Phase 1: h = tanh(enc+dec) -> LDS bf16, float4-vectorized ----
    {
        const int j0 = (tid & 127) * 4;
        const int ug = tid >> 7;
        const float4 e = *(const float4*)(enc_proj + (size_t)bt * DJ + j0);
        const float* dp = dec_proj + (size_t)(b * NU + ug * 16) * DJ + j0;
        const int chunk = j0 >> 3;
        const int wi = j0 & 7;
        #pragma unroll 4
        for (int i = 0; i < 16; i++) {
            const int u = ug * 16 + i;
            float4 d = *(const float4*)(dp + (size_t)i * DJ);
            float x0 = e.x + d.x, x1 = e.y + d.y, x2 = e.z + d.z, x3 = e.w + d.w;
            ushort4 o;
            o.x = f2bf(1.f - 2.f / (__expf(2.f * x0) + 1.f));
            o.y = f2bf(1.f - 2.f / (__expf(2.f * x1) + 1.f));
            o.z = f2bf(1.f - 2.f / (__expf(2.f * x2) + 1.f));
            o.w = f2bf(1.f - 2.f / (__expf(2.f * x3) + 1.f));
            *(ushort4*)(ha + (size_t)u * DJ + (((chunk ^ (u & 7)) << 3) + wi)) = o;
        }
    }
    __syncthreads();

    const int w = tid >> 6;
    const int lane = tid & 63;
    const int q = lane >> 4;
    const int nn = lane & 15;
    const int wbase = w * 128;

    // B global sources (per-lane; identical addresses to round-6 bv loads)
    const unsigned short* gpL = W2b + (size_t)(wbase + nn * 4) * DJ + q * 8;
    const unsigned short* gpH = gpL + (size_t)64 * DJ;

    // per-wave LDS chunks (wave-uniform bases; HW appends lane*16 bytes)
    unsigned short* ldsL = Bb0 + w * 2048;   // 4 KB per wave (2048 ushorts)
    unsigned short* ldsH = Bb1 + w * 2048;
    // lane's read-back offset within chunk: c4*512 + lane*8 (ushorts)
    const int lrd = lane * 8;

    floatx4 acc[4][8];
    #pragma unroll
    for (int rt = 0; rt < 4; rt++)
        #pragma unroll
        for (int ct = 0; ct < 8; ct++)
            acc[rt][ct] = (floatx4){0.f, 0.f, 0.f, 0.f};

    short8 av[4];
    short8 bv[4];

    // ---- prologue: stage Low(ks=0) -> Bb0 ----
    #pragma unroll
    for (int c4 = 0; c4 < 4; c4++)
        gll16(gpL + (size_t)c4 * DJ, ldsL + c4 * 512);

    // ---- K-loop: 16 steps of k=32; each step = Low half then High half ----
    for (int ks = 0; ks < 16; ks++) {
        // stage High(ks) -> Bb1   (outstanding: H(4) + L(4))
        #pragma unroll
        for (int c4 = 0; c4 < 4; c4++)
            gll16(gpH + (size_t)c4 * DJ + ks * 32, ldsH + c4 * 512);

        // A fragments for this k-slice (shared by both halves)
        #pragma unroll
        for (int rt = 0; rt < 4; rt++) {
            const int u2 = rt * 16 + nn;
            const int c = ((ks * 4 + q) ^ (u2 & 7)) << 3;
            av[rt] = *(const short8*)(ha + (size_t)u2 * DJ + c);
        }

        // wait Low(ks) landed (leave High's 4 in flight)
        asm volatile("s_waitcnt vmcnt(4)" ::: "memory");
        __builtin_amdgcn_sched_barrier(0);
        #pragma unroll
        for (int c4 = 0; c4 < 4; c4++)
            bv[c4] = *(const short8*)(ldsL + c4 * 512 + lrd);
        #pragma unroll
        for (int c4 = 0; c4 < 4; c4++)
            #pragma unroll
            for (int rt = 0; rt < 4; rt++)
                acc[rt][c4] = __builtin_amdgcn_mfma_f32_16x16x32_bf16(
                    av[rt], bv[c4], acc[rt][c4], 0, 0, 0);

        // stage Low(ks+1) -> Bb0 (skip on last step)
        if (ks + 1 < 16) {
            #pragma unroll
            for (int c4 = 0; c4 < 4; c4++)
                gll16(gpL + (size_t)c4 * DJ + (ks + 1) * 32, ldsL + c4 * 512);
            asm volatile("s_waitcnt vmcnt(4)" ::: "memory");   // High(ks) done
        } else {
            asm volatile("s_waitcnt vmcnt(0)" ::: "memory");   // drain tail
        }
        __builtin_amdgcn_sched_barrier(0);
        #pragma unroll
        for (int c4 = 0; c4 < 4; c4++)
            bv[c4] = *(const short8*)(ldsH + c4 * 512 + lrd);
        #pragma unroll
        for (int c4 = 0; c4 < 4; c4++)
            #pragma unroll
            for (int rt = 0; rt < 4; rt++)
                acc[rt][4 + c4] = __builtin_amdgcn_mfma_f32_16x16x32_bf16(
                    av[rt], bv[c4], acc[rt][4 + c4], 0, 0, 0);
    }

    __syncthreads();   // ha/B dead from here; reuse smem for reductions

    float* wred     = (float*)smem;               // [64][8]
    float* rowoff_s = (float*)(smem + 2048);      // [64]

    // bias add (lane's 8 cols: wbase+nn*4+{0..3}, wbase+64+nn*4+{0..3})
    float b2a[8];
    *(float4*)&b2a[0] = *(const float4*)(b2 + wbase + nn * 4);
    *(float4*)&b2a[4] = *(const float4*)(b2 + wbase + 64 + nn * 4);
    #pragma unroll
    for (int rt = 0; rt < 4; rt++)
        #pragma unroll
        for (int ct = 0; ct < 8; ct++)
            #pragma unroll
            for (int r = 0; r < 4; r++)
                acc[rt][ct][r] += b2a[ct];

    // per-row sum of exp (no max: |logit| < ~23, fp32-safe)
    #pragma unroll
    for (int rt = 0; rt < 4; rt++) {
        #pragma unroll
        for (int r = 0; r < 4; r++) {
            float s = 0.f;
            #pragma unroll
            for (int ct = 0; ct < 8; ct++) s += __expf(acc[rt][ct][r]);
            #pragma unroll
            for (int mk = 1; mk <= 8; mk <<= 1) s += __shfl_xor(s, mk, 64);
            if (nn == 0) wred[(rt * 16 + q * 4 + r) * 8 + w] = s;
        }
    }
    __syncthreads();
    if (tid < 64) {
        float4 s0 = *(const float4*)&wred[tid * 8];
        float4 s1 = *(const float4*)&wred[tid * 8 + 4];
        float s = ((s0.x + s0.y) + (s0.z + s0.w)) + ((s1.x + s1.y) + (s1.z + s1.w));
        rowoff_s[tid] = __logf(s);
    }
    __syncthreads();

    // store: out[bt*64+u][v] = logit - log(sum); 2x nt dwordx4 per (rt,r)
    float* outb = out + (size_t)bt * NU * DV;
    #pragma unroll
    for (int rt = 0; rt < 4; rt++) {
        #pragma unroll
        for (int r = 0; r < 4; r++) {
            const int u = rt * 16 + q * 4 + r;
            const float off = rowoff_s[u];
            floatx4 v0, v1;
            v0[0] = acc[rt][0][r] - off; v0[1] = acc[rt][1][r] - off;
            v0[2] = acc[rt][2][r] - off; v0[3] = acc[rt][3][r] - off;
            v1[0] = acc[rt][4][r] - off; v1[1] = acc[rt][5][r] - off;
            v1[2] = acc[rt][6][r] - off; v1[3] = acc[rt][7][r] - off;
            __builtin_nontemporal_store(v0, (floatx4*)(outb + (size_t)u * DV + wbase + nn * 4));
            __builtin_nontemporal_store(v1, (floatx4*)(outb + (size_t)u * DV + wbase + 64 + nn * 4));
        }
    }
}

// ---------------------------------------------------------------------------
extern "C" void kernel_launch(void* const* d_in, const int* in_sizes, int n_in,
                              void* d_out, int out_size, void* d_ws, size_t ws_size,
                              hipStream_t stream) {
    const float* enc = (const float*)d_in[0];   // (8,256,256)
    const float* dec = (const float*)d_in[1];   // (8,64,256)
    const float* W1  = (const float*)d_in[2];   // (512,512)
    const float* b1  = (const float*)d_in[3];   // (512,)
    const float* W2  = (const float*)d_in[4];   // (1024,512)
    const float* b2  = (const float*)d_in[5];   // (1024,)
    float* out = (float*)d_out;                 // (8,256,64,1024)

    // workspace: enc_proj (2048x512 f32) | dec_proj (512x512 f32) | W2 bf16
    float* enc_proj = (float*)d_ws;
    float* dec_proj = enc_proj + (size_t)(NB * NT) * DJ;
    unsigned short* W2b = (unsigned short*)(dec_proj + (size_t)DJ * DJ);

    dim3 g1(8, 40);
    stage1_gemm<<<g1, 256, 0, stream>>>(enc, dec, W1, b1, enc_proj, dec_proj);
    convert_w2<<<512, 256, 0, stream>>>(W2, W2b);
    joint_kernel<<<NB * NT, 512, 0, stream>>>(enc_proj, dec_proj, W2b, b2, out);
}